// Round 2
// baseline (349.535 us; speedup 1.0000x reference)
//
#include <hip/hip_runtime.h>

// Problem constants (x: (512, 9, 84, 84) f32)
#define N_ELEM   7056        // 84*84
#define DIM      84
#define M_STEPS  14111       // 2*N_ELEM - 1
#define N_ROWS   4608        // 512*9
#define NCHUNK   64
#define KSTEPS   221         // ceil(M_STEPS / NCHUNK)
#define WIN      392         // max window width = (KSTEPS-1) + 2*DIM + 1 = 389, padded
#define TPB      256
#define JPT      28          // ceil(N_ELEM / TPB)

// ---- JAX threefry2x32 block cipher (20 rounds), bit-exact port ----
__device__ __forceinline__ void threefry2x32(unsigned k0, unsigned k1,
                                             unsigned x0, unsigned x1,
                                             unsigned &o0, unsigned &o1) {
  const unsigned ks0 = k0, ks1 = k1, ks2 = k0 ^ k1 ^ 0x1BD11BDAu;
  x0 += ks0; x1 += ks1;
#define ROTL(x, r) (((x) << (r)) | ((x) >> (32 - (r))))
#define RND(r) { x0 += x1; x1 = ROTL(x1, r); x1 ^= x0; }
  RND(13) RND(15) RND(26) RND(6)
  x0 += ks1; x1 += ks2 + 1u;
  RND(17) RND(29) RND(16) RND(24)
  x0 += ks2; x1 += ks0 + 2u;
  RND(13) RND(15) RND(26) RND(6)
  x0 += ks0; x1 += ks1 + 3u;
  RND(17) RND(29) RND(16) RND(24)
  x0 += ks1; x1 += ks2 + 4u;
  RND(13) RND(15) RND(26) RND(6)
  x0 += ks2; x1 += ks0 + 5u;
  o0 = x0; o1 = x1;
#undef RND
#undef ROTL
}

// jax.random.choice(key,5,p=[.55,.1125,.1125,.1125,.1125]) sample from raw bits.
// r = cum[-1]*(1-u), idx = searchsorted(cum, r, 'left') = #(cum[j] < r).
// f32 sequential cumsum verified in exact arithmetic:
//   q = (0.55000001, 0.66250001, 0.77500004, 0.88750005, 1.0f exactly).
__device__ __forceinline__ int r_from_bits(unsigned bits) {
  const float p8 = 0.1125f;
  const float q0 = 0.55f;
  const float q1 = q0 + p8;
  const float q2 = q1 + p8;
  const float q3 = q2 + p8;
  const float q4 = q3 + p8;
  float u  = __uint_as_float((bits >> 9) | 0x3F800000u) - 1.0f; // [0,1)
  float rv = q4 * (1.0f - u);
  return (int)(q0 < rv) + (int)(q1 < rv) + (int)(q2 < rv) + (int)(q3 < rv);
}

// Window bounds for chunk c: steps t in [t0,t1), positions touched are within
// [imin-DIM, imax+DIM] clamped to [0, N_ELEM-1], where i(t) = |t - (N_ELEM-1)|.
__device__ __forceinline__ void chunk_bounds(int c, int &t0, int &t1, int &lo, int &hi) {
  t0 = c * KSTEPS;
  t1 = t0 + KSTEPS; if (t1 > M_STEPS) t1 = M_STEPS;
  int a0 = t0 - (N_ELEM - 1);      if (a0 < 0) a0 = -a0;
  int a1 = (t1 - 1) - (N_ELEM - 1); if (a1 < 0) a1 = -a1;
  int imax = a0 > a1 ? a0 : a1;
  int imin;
  if (t0 <= N_ELEM - 1 && t1 - 1 >= N_ELEM - 1) imin = 0;
  else imin = a0 < a1 ? a0 : a1;
  lo = imin - DIM; if (lo < 0) lo = 0;
  hi = imax + DIM; if (hi > N_ELEM - 1) hi = N_ELEM - 1;
}

// Single workgroup: compute perm[0..N_ELEM) into global ws.
//   A: threefry (PARTITIONABLE mode: counter=(0,t), bits=y0^y1) -> r_t per step
//   B: 64 chunks of 221 sequential swaps, each in its own LDS window (wave 0)
//   C: compose: y = rho_0(rho_1(...rho_63(x))) — backward over chunks,
//      28 independent chains per thread for latency hiding.
__global__ __launch_bounds__(TPB) void perm_kernel(int* __restrict__ permG) {
  __shared__ unsigned char  rs[M_STEPS + 1];            // 14112 B
  __shared__ unsigned short win[NCHUNK * WIN];          // 50176 B  (total 62.8 KB)

  const int tid = threadIdx.x;

  // ---- init windows to identity ----
  for (int f = tid; f < NCHUNK * WIN; f += TPB) {
    int c = f / WIN, e = f - c * WIN;
    int t0, t1, lo, hi; chunk_bounds(c, t0, t1, lo, hi);
    int v = lo + e; if (v > N_ELEM - 1) v = N_ELEM - 1;  // pad entries unused
    win[f] = (unsigned short)v;
  }

  // ---- phase A: random draws (jax_threefry_partitionable=True semantics) ----
  // bits[t] = b1 ^ b2 where (b1,b2) = threefry2x32(key=(0,42), counter=(hi=0, lo=t)).
  for (int t = tid; t < M_STEPS; t += TPB) {
    unsigned y0, y1;
    threefry2x32(0u, 42u, 0u, (unsigned)t, y0, y1);
    rs[t] = (unsigned char)r_from_bits(y0 ^ y1);
  }
  __syncthreads();

  // ---- phase B: per-chunk sequential swaps (wave 0, one chunk per lane) ----
  if (tid < NCHUNK) {
    int t0, t1, lo, hi; chunk_bounds(tid, t0, t1, lo, hi);
    unsigned short* w = &win[tid * WIN];
    for (int t = t0; t < t1; ++t) {
      int i = t - (N_ELEM - 1); if (i < 0) i = -i;
      int r = rs[t];
      int off = (r == 1) ? 1 : (r == 2) ? -1 : (r == 3) ? DIM : (r == 4) ? -DIM : 0;
      int idx = i + off;
      bool doit = (r != 0) && (idx > 0) && (idx < N_ELEM);
      if (doit) {                     // idx in (0, N_ELEM) -> no clamp needed
        unsigned short a = w[i   - lo];
        unsigned short b = w[idx - lo];
        w[i   - lo] = b;
        w[idx - lo] = a;
      }
    }
  }
  __syncthreads();

  // ---- phase C: compose all chunk permutations ----
  int y[JPT];
#pragma unroll
  for (int j = 0; j < JPT; ++j) y[j] = j * TPB + tid;   // tail ids >= N stay outside all windows

  for (int c = NCHUNK - 1; c >= 0; --c) {
    int t0, t1, lo, hi; chunk_bounds(c, t0, t1, lo, hi);
    int wm1 = hi - lo;
    const unsigned short* w = &win[c * WIN];
#pragma unroll
    for (int j = 0; j < JPT; ++j) {
      int e = y[j] - lo;
      bool in = (unsigned)e <= (unsigned)wm1;
      int ec = in ? e : 0;
      int v = (int)w[ec];
      y[j] = in ? v : y[j];
    }
  }

#pragma unroll
  for (int j = 0; j < JPT; ++j) {
    int xid = j * TPB + tid;
    if (xid < N_ELEM) permG[xid] = y[j];
  }
}

// out[row, j] = x[row, perm[j]] for row in [0, 4608), j in [0, 7056)
#define ROWS_PER_BLOCK 16
__global__ __launch_bounds__(TPB) void gather_kernel(const float* __restrict__ x,
                                                     const int* __restrict__ perm,
                                                     float* __restrict__ out) {
  int j  = blockIdx.x * TPB + threadIdx.x;
  int r0 = blockIdx.y * ROWS_PER_BLOCK;
  bool valid = (j < N_ELEM);
  int pj = valid ? perm[j] : 0;
  const float* xb = x   + (size_t)r0 * N_ELEM;
  float*       ob = out + (size_t)r0 * N_ELEM;
#pragma unroll
  for (int rr = 0; rr < ROWS_PER_BLOCK; ++rr) {
    if (valid) ob[(size_t)rr * N_ELEM + j] = xb[(size_t)rr * N_ELEM + pj];
  }
}

extern "C" void kernel_launch(void* const* d_in, const int* in_sizes, int n_in,
                              void* d_out, int out_size, void* d_ws, size_t ws_size,
                              hipStream_t stream) {
  const float* x = (const float*)d_in[0];
  float* out = (float*)d_out;
  int* perm = (int*)d_ws;   // 7056 * 4 B scratch

  perm_kernel<<<1, TPB, 0, stream>>>(perm);

  dim3 grid((N_ELEM + TPB - 1) / TPB, N_ROWS / ROWS_PER_BLOCK); // (28, 288)
  gather_kernel<<<grid, TPB, 0, stream>>>(x, perm, out);
}

// Round 3
// 275.434 us; speedup vs baseline: 1.2690x; 1.2690x over previous
//
#include <hip/hip_runtime.h>

// Problem constants (x: (512, 9, 84, 84) f32)
#define N_ELEM   7056        // 84*84
#define DIM      84
#define M_STEPS  14111       // 2*N_ELEM - 1
#define N_ROWS   4608        // 512*9
#define NCHUNK   96
#define KSTEPS   147         // 96*147 = 14112 >= 14111
#define WINW     320         // window width: (K-1)+2*84+1 = 315, padded to 320 (640 B, 16B-mult)
#define TPB      256

// ---- JAX threefry2x32 block cipher (20 rounds), bit-exact port ----
__device__ __forceinline__ void threefry2x32(unsigned k0, unsigned k1,
                                             unsigned x0, unsigned x1,
                                             unsigned &o0, unsigned &o1) {
  const unsigned ks0 = k0, ks1 = k1, ks2 = k0 ^ k1 ^ 0x1BD11BDAu;
  x0 += ks0; x1 += ks1;
#define ROTL(x, r) (((x) << (r)) | ((x) >> (32 - (r))))
#define RND(r) { x0 += x1; x1 = ROTL(x1, r); x1 ^= x0; }
  RND(13) RND(15) RND(26) RND(6)
  x0 += ks1; x1 += ks2 + 1u;
  RND(17) RND(29) RND(16) RND(24)
  x0 += ks2; x1 += ks0 + 2u;
  RND(13) RND(15) RND(26) RND(6)
  x0 += ks0; x1 += ks1 + 3u;
  RND(17) RND(29) RND(16) RND(24)
  x0 += ks1; x1 += ks2 + 4u;
  RND(13) RND(15) RND(26) RND(6)
  x0 += ks2; x1 += ks0 + 5u;
  o0 = x0; o1 = x1;
#undef RND
#undef ROTL
}

// jax.random.choice(key,5,p=[.55,.1125,.1125,.1125,.1125]) — searchsorted on f32 cumsum
// (sequential f32 cumsum verified exact-arithmetic: q4 == 1.0f exactly).
__device__ __forceinline__ int r_from_bits(unsigned bits) {
  const float p8 = 0.1125f;
  const float q0 = 0.55f;
  const float q1 = q0 + p8;
  const float q2 = q1 + p8;
  const float q3 = q2 + p8;
  const float q4 = q3 + p8;
  float u  = __uint_as_float((bits >> 9) | 0x3F800000u) - 1.0f; // [0,1)
  float rv = q4 * (1.0f - u);
  return (int)(q0 < rv) + (int)(q1 < rv) + (int)(q2 < rv) + (int)(q3 < rv);
}

// Window bounds for chunk c: steps t in [t0,t1); touched positions are within
// [imin-DIM, imax+DIM] clamped to [0, N_ELEM-1], where i(t) = |t - (N_ELEM-1)|.
__device__ __forceinline__ void chunk_bounds(int c, int &t0, int &t1, int &lo, int &hi) {
  t0 = c * KSTEPS;
  t1 = t0 + KSTEPS; if (t1 > M_STEPS) t1 = M_STEPS;
  int a0 = t0 - (N_ELEM - 1);       if (a0 < 0) a0 = -a0;
  int a1 = (t1 - 1) - (N_ELEM - 1); if (a1 < 0) a1 = -a1;
  int imax = a0 > a1 ? a0 : a1;
  int imin;
  if (t0 <= N_ELEM - 1 && t1 - 1 >= N_ELEM - 1) imin = 0;
  else imin = a0 < a1 ? a0 : a1;
  lo = imin - DIM; if (lo < 0) lo = 0;
  hi = imax + DIM; if (hi > N_ELEM - 1) hi = N_ELEM - 1;
}

// Kernel 1: one block per chunk (chunks are independent — each starts from an
// identity window). Parallel threefry for the chunk's draws, then lane 0 runs
// the K sequential swaps in a private LDS window; window written to global ws.
__global__ __launch_bounds__(TPB) void chunk_kernel(unsigned* __restrict__ winG) {
  __shared__ __align__(16) unsigned short w[WINW];
  __shared__ unsigned char rs[KSTEPS + 1];

  const int c = blockIdx.x, tid = threadIdx.x;
  int t0, t1, lo, hi; chunk_bounds(c, t0, t1, lo, hi);
  const int nt = t1 - t0;

  for (int e = tid; e < WINW; e += TPB) w[e] = (unsigned short)(lo + e);
  if (tid < nt) {
    unsigned y0, y1;
    threefry2x32(0u, 42u, 0u, (unsigned)(t0 + tid), y0, y1);
    rs[tid] = (unsigned char)r_from_bits(y0 ^ y1);
  }
  __syncthreads();

  if (tid == 0) {
    for (int k = 0; k < nt; ++k) {
      int t = t0 + k;
      int i = t - (N_ELEM - 1); if (i < 0) i = -i;
      int r = rs[k];
      int off = (r == 1) ? 1 : (r == 2) ? -1 : (r == 3) ? DIM : (r == 4) ? -DIM : 0;
      int idx = i + off;
      bool doit = (r != 0) && (idx > 0) && (idx < N_ELEM);
      int je = doit ? idx : i;              // branchless self-swap when !doit
      unsigned short a = w[i  - lo];
      unsigned short b = w[je - lo];
      w[i  - lo] = b;
      w[je - lo] = a;
    }
  }
  __syncthreads();

  // write 160 dwords per chunk, coalesced
  const unsigned* ws32 = (const unsigned*)w;
  if (tid < WINW / 2) winG[c * (WINW / 2) + tid] = ws32[tid];
}

// Kernel 2: compose. Each block loads ALL windows (61.4 KB LDS) and traces 252
// indices backward through the 96 chunk permutations. A given index is inside
// only ~4-5 windows and consecutive indices are wave-coherent -> branchy skip.
#define TRACE_BLOCKS 28        // 28 * 252 = 7056
__global__ __launch_bounds__(TPB) void trace_kernel(const unsigned* __restrict__ winG,
                                                    int* __restrict__ permG) {
  __shared__ __align__(16) unsigned short w[NCHUNK * WINW];  // 61440 B
  const int tid = threadIdx.x;

  uint4* w4 = (uint4*)w;
  const uint4* g4 = (const uint4*)winG;
  const int n4 = (NCHUNK * WINW * 2) / 16;   // 3840 uint4
  for (int k = tid; k < n4; k += TPB) w4[k] = g4[k];
  __syncthreads();

  if (tid < 252) {
    int y = blockIdx.x * 252 + tid;
    for (int c = NCHUNK - 1; c >= 0; --c) {
      int t0, t1, lo, hi; chunk_bounds(c, t0, t1, lo, hi);
      unsigned e = (unsigned)(y - lo);
      if (e <= (unsigned)(hi - lo)) y = (int)w[c * WINW + e];
    }
    permG[blockIdx.x * 252 + tid] = y;
  }
}

// Kernel 3: out[row, 4j..4j+3] = x[row, perm[4j..4j+3]] — int4 perm load,
// 4 scattered dword reads, one coalesced float4 store per row.
#define GROWS 16
#define NJV   (N_ELEM / 4)     // 1764
__global__ __launch_bounds__(TPB) void gather_kernel(const float* __restrict__ x,
                                                     const int* __restrict__ perm,
                                                     float* __restrict__ out) {
  int jv = blockIdx.x * TPB + threadIdx.x;
  bool valid = (jv < NJV);
  int4 p = valid ? ((const int4*)perm)[jv] : make_int4(0, 0, 0, 0);
  int r0 = blockIdx.y * GROWS;
  const float* xb = x   + (size_t)r0 * N_ELEM;
  float*       ob = out + (size_t)r0 * N_ELEM;
#pragma unroll
  for (int rr = 0; rr < GROWS; ++rr) {
    const float* xr = xb + (size_t)rr * N_ELEM;
    float4 v;
    v.x = xr[p.x]; v.y = xr[p.y]; v.z = xr[p.z]; v.w = xr[p.w];
    if (valid) ((float4*)(ob + (size_t)rr * N_ELEM))[jv] = v;
  }
}

extern "C" void kernel_launch(void* const* d_in, const int* in_sizes, int n_in,
                              void* d_out, int out_size, void* d_ws, size_t ws_size,
                              hipStream_t stream) {
  const float* x = (const float*)d_in[0];
  float* out = (float*)d_out;

  unsigned* winG = (unsigned*)d_ws;                      // 96*320*2 = 61440 B
  int* perm = (int*)((char*)d_ws + NCHUNK * WINW * 2);   // 7056*4 = 28224 B

  chunk_kernel<<<NCHUNK, TPB, 0, stream>>>(winG);
  trace_kernel<<<TRACE_BLOCKS, TPB, 0, stream>>>(winG, perm);

  dim3 grid((NJV + TPB - 1) / TPB, N_ROWS / GROWS);      // (7, 288)
  gather_kernel<<<grid, TPB, 0, stream>>>(x, perm, out);
}

// Round 4
// 268.038 us; speedup vs baseline: 1.3040x; 1.0276x over previous
//
#include <hip/hip_runtime.h>

// Problem constants (x: (512, 9, 84, 84) f32)
#define N_ELEM   7056        // 84*84
#define DIM      84
#define M_STEPS  14111       // 2*N_ELEM - 1
#define N_ROWS   4608        // 512*9
#define NCHUNK   384
#define KSTEPS   37          // 384*37 = 14208 >= 14111 (tail chunks empty -> identity)
#define WINW     208         // window: (K-1)+2*84+1 = 205, padded to 208 (416 B = 26 uint4)
#define TPB      256
#define NJV      1764        // N_ELEM / 4

// ---- JAX threefry2x32 block cipher (20 rounds), bit-exact port ----
__device__ __forceinline__ void threefry2x32(unsigned k0, unsigned k1,
                                             unsigned x0, unsigned x1,
                                             unsigned &o0, unsigned &o1) {
  const unsigned ks0 = k0, ks1 = k1, ks2 = k0 ^ k1 ^ 0x1BD11BDAu;
  x0 += ks0; x1 += ks1;
#define ROTL(x, r) (((x) << (r)) | ((x) >> (32 - (r))))
#define RND(r) { x0 += x1; x1 = ROTL(x1, r); x1 ^= x0; }
  RND(13) RND(15) RND(26) RND(6)
  x0 += ks1; x1 += ks2 + 1u;
  RND(17) RND(29) RND(16) RND(24)
  x0 += ks2; x1 += ks0 + 2u;
  RND(13) RND(15) RND(26) RND(6)
  x0 += ks0; x1 += ks1 + 3u;
  RND(17) RND(29) RND(16) RND(24)
  x0 += ks1; x1 += ks2 + 4u;
  RND(13) RND(15) RND(26) RND(6)
  x0 += ks2; x1 += ks0 + 5u;
  o0 = x0; o1 = x1;
#undef RND
#undef ROTL
}

// jax.random.choice(key,5,p=[.55,.1125,.1125,.1125,.1125]) — searchsorted on f32
// cumsum (sequential f32 cumsum verified exact-arithmetic: q4 == 1.0f exactly).
// Partitionable-threefry bits: b1 ^ b2 with counter (0, t).
__device__ __forceinline__ int r_from_bits(unsigned bits) {
  const float p8 = 0.1125f;
  const float q0 = 0.55f;
  const float q1 = q0 + p8;
  const float q2 = q1 + p8;
  const float q3 = q2 + p8;
  const float q4 = q3 + p8;
  float u  = __uint_as_float((bits >> 9) | 0x3F800000u) - 1.0f; // [0,1)
  float rv = q4 * (1.0f - u);
  return (int)(q0 < rv) + (int)(q1 < rv) + (int)(q2 < rv) + (int)(q3 < rv);
}

// Window bounds for chunk c: steps t in [t0,t1); touched positions are within
// [imin-DIM, imax+DIM] clamped to [0, N_ELEM-1], where i(t) = |t - (N_ELEM-1)|.
// t0 clamped so tail chunks past M_STEPS become empty (identity windows).
__device__ __forceinline__ void chunk_bounds(int c, int &t0, int &t1, int &lo, int &hi) {
  t0 = c * KSTEPS; if (t0 > M_STEPS) t0 = M_STEPS;
  t1 = t0 + KSTEPS; if (t1 > M_STEPS) t1 = M_STEPS;
  int a0 = t0 - (N_ELEM - 1);       if (a0 < 0) a0 = -a0;
  int a1 = (t1 - 1) - (N_ELEM - 1); if (a1 < 0) a1 = -a1;
  int imax = a0 > a1 ? a0 : a1;
  int imin;
  if (t0 <= N_ELEM - 1 && t1 - 1 >= N_ELEM - 1) imin = 0;
  else imin = a0 < a1 ? a0 : a1;
  lo = imin - DIM; if (lo < 0) lo = 0;
  hi = imax + DIM; if (hi > N_ELEM - 1) hi = N_ELEM - 1;
}

// Kernel 1: one block per chunk (chunks independent, each starts from identity).
// Parallel threefry for the chunk's draws, then lane 0 runs the <=37 sequential
// swaps in a private LDS window; window written to global ws (26 uint4).
__global__ __launch_bounds__(TPB) void chunk_kernel(unsigned* __restrict__ winG) {
  __shared__ __align__(16) unsigned short w[WINW];
  __shared__ unsigned char rs[KSTEPS + 3];

  const int c = blockIdx.x, tid = threadIdx.x;
  int t0, t1, lo, hi; chunk_bounds(c, t0, t1, lo, hi);
  const int nt = t1 - t0;

  if (tid < WINW) w[tid] = (unsigned short)(lo + tid);   // pad entries unused
  if (tid < nt) {
    unsigned y0, y1;
    threefry2x32(0u, 42u, 0u, (unsigned)(t0 + tid), y0, y1);
    rs[tid] = (unsigned char)r_from_bits(y0 ^ y1);
  }
  __syncthreads();

  if (tid == 0) {
    for (int k = 0; k < nt; ++k) {
      int t = t0 + k;
      int i = t - (N_ELEM - 1); if (i < 0) i = -i;
      int r = rs[k];
      int off = (r == 1) ? 1 : (r == 2) ? -1 : (r == 3) ? DIM : (r == 4) ? -DIM : 0;
      int idx = i + off;
      bool doit = (r != 0) && (idx > 0) && (idx < N_ELEM);
      int je = doit ? idx : i;              // branchless self-swap when !doit
      unsigned short a = w[i  - lo];
      unsigned short b = w[je - lo];
      w[i  - lo] = b;
      w[je - lo] = a;
    }
  }
  __syncthreads();

  const uint4* w4 = (const uint4*)w;
  if (tid < WINW * 2 / 16) ((uint4*)winG)[c * (WINW * 2 / 16) + tid] = w4[tid];
}

// Kernel 2: compose. 3 passes of 128 windows (53 KB LDS each); each of 28
// blocks traces 252 indices backward through chunks c = 383..0.
#define TRACE_BLOCKS 28        // 28 * 252 = 7056
#define WPP 128                // windows per pass
__global__ __launch_bounds__(TPB) void trace_kernel(const unsigned* __restrict__ winG,
                                                    int* __restrict__ permG) {
  __shared__ __align__(16) unsigned short w[WPP * WINW];  // 53248 B
  const int tid = threadIdx.x;
  const int U4_PER_WIN = WINW * 2 / 16;                   // 26

  int y = blockIdx.x * 252 + tid;                         // traced index (tid<252)

  for (int pass = NCHUNK / WPP - 1; pass >= 0; --pass) {
    const int cbase = pass * WPP;
    uint4* w4 = (uint4*)w;
    const uint4* g4 = (const uint4*)winG + cbase * U4_PER_WIN;
    for (int k = tid; k < WPP * U4_PER_WIN; k += TPB) w4[k] = g4[k];
    __syncthreads();

    if (tid < 252) {
      for (int c = WPP - 1; c >= 0; --c) {
        int t0, t1, lo, hi; chunk_bounds(cbase + c, t0, t1, lo, hi);
        unsigned e = (unsigned)(y - lo);
        if (e <= (unsigned)(hi - lo)) y = (int)w[c * WINW + e];
      }
    }
    __syncthreads();   // before next pass overwrites LDS
  }

  if (tid < 252) permG[blockIdx.x * 252 + tid] = y;
}

// Kernel 3: per-row LDS-staged gather. perm[j] indexes WITHIN the row, so the
// whole 28 KB row fits in LDS: coalesced float4 row load -> LDS permute ->
// coalesced float4 store. Fully coalesced in both global directions.
__global__ __launch_bounds__(TPB) void gather_kernel(const float* __restrict__ x,
                                                     const int* __restrict__ perm,
                                                     float* __restrict__ out) {
  __shared__ __align__(16) float row[N_ELEM];             // 28224 B -> 2 blocks/CU
  const int r = blockIdx.x;
  const int tid = threadIdx.x;

  const float4* xr4 = (const float4*)(x + (size_t)r * N_ELEM);
  float4* row4 = (float4*)row;
  for (int v = tid; v < NJV; v += TPB) row4[v] = xr4[v];
  __syncthreads();

  float4* or4 = (float4*)(out + (size_t)r * N_ELEM);
  const int4* p4 = (const int4*)perm;
  for (int v = tid; v < NJV; v += TPB) {
    int4 p = p4[v];
    float4 o;
    o.x = row[p.x]; o.y = row[p.y]; o.z = row[p.z]; o.w = row[p.w];
    or4[v] = o;
  }
}

extern "C" void kernel_launch(void* const* d_in, const int* in_sizes, int n_in,
                              void* d_out, int out_size, void* d_ws, size_t ws_size,
                              hipStream_t stream) {
  const float* x = (const float*)d_in[0];
  float* out = (float*)d_out;

  unsigned* winG = (unsigned*)d_ws;                        // 384*416 = 159744 B
  int* perm = (int*)((char*)d_ws + NCHUNK * WINW * 2);     // 7056*4  =  28224 B

  chunk_kernel<<<NCHUNK, TPB, 0, stream>>>(winG);
  trace_kernel<<<TRACE_BLOCKS, TPB, 0, stream>>>(winG, perm);
  gather_kernel<<<N_ROWS, TPB, 0, stream>>>(x, perm, out);
}